// Round 7
// baseline (156.399 us; speedup 1.0000x reference)
//
#include <hip/hip_runtime.h>

#define T_ 4
#define B_ 8
#define N_ 1024
#define C_ 512
#define H_ 8
#define D_ 64
#define M_ (T_*B_*N_)   // 32768 rows
#define TB_ (T_*B_)     // 32

typedef __bf16 bf16;
typedef __bf16 bf16x4 __attribute__((ext_vector_type(4)));
typedef __bf16 bf16x8 __attribute__((ext_vector_type(8)));
typedef float f32x4 __attribute__((ext_vector_type(4)));

__device__ __forceinline__ void gload16(const void* g, void* l) {
  __builtin_amdgcn_global_load_lds(
      (const __attribute__((address_space(1))) void*)g,
      (__attribute__((address_space(3))) void*)l, 16, 0, 0);
}

struct PtrPack { const float* p[24]; };

// ---- fold BN into weights for all 4 mats ----
__global__ __launch_bounds__(256)
void prep_all(PtrPack pk, bf16* __restrict__ WB, float* __restrict__ BS) {
  const int mat = blockIdx.x >> 9, d = blockIdx.x & 511;
  const float* W    = pk.p[6*mat + 0];
  const float* b    = pk.p[6*mat + 1];
  const float* g    = pk.p[6*mat + 2];
  const float* beta = pk.p[6*mat + 3];
  const float* mu   = pk.p[6*mat + 4];
  const float* var  = pk.p[6*mat + 5];
  float s = g[d] * rsqrtf(var[d] + 1e-5f);
  if (threadIdx.x == 0) BS[mat*512 + d] = (b[d] - mu[d]) * s + beta[d];
  bf16* Wout = WB + (size_t)mat * 262144 + (size_t)d * 512;
  for (int c = threadIdx.x; c < 512; c += 256)
    Wout[c] = (bf16)(W[(size_t)d * 512 + c] * s);
}

// ---- WqT[c][d] = Wq[d][c] * sq[d] ----
__global__ __launch_bounds__(256)
void prep_wqT(const float* __restrict__ W, const float* __restrict__ g,
              const float* __restrict__ var, bf16* __restrict__ WqT) {
  const int di = blockIdx.x >> 3, ci = blockIdx.x & 7;
  const int t = threadIdx.x;
  __shared__ float lds[64][65];
  const int rgrp = t >> 4, k = t & 15;
#pragma unroll
  for (int p = 0; p < 4; p++) {
    int r = p * 16 + rgrp;
    int d = di * 64 + r;
    float s = g[d] * rsqrtf(var[d] + 1e-5f);
    float4 v = *(const float4*)(W + (size_t)d * 512 + ci * 64 + k * 4);
    lds[r][k*4+0] = v.x * s; lds[r][k*4+1] = v.y * s;
    lds[r][k*4+2] = v.z * s; lds[r][k*4+3] = v.w * s;
  }
  __syncthreads();
#pragma unroll
  for (int p = 0; p < 16; p++) {
    int c = p * 4 + (t >> 6), dd = t & 63;
    WqT[(size_t)(ci*64 + c) * 512 + di*64 + dd] = (bf16)lds[dd][c];
  }
}

// ---- x -> xb + xT + col-sum partials ----
__global__ __launch_bounds__(256)
void cvt_x_t(const float* __restrict__ x, bf16* __restrict__ xb,
             bf16* __restrict__ xT, float* __restrict__ spart) {
  const int bid = blockIdx.x;
  const int tb = bid >> 7, nc = (bid >> 3) & 15, cc = bid & 7;
  const int t = threadIdx.x;
  __shared__ float lds[64][65];
  __shared__ float sred[16][64];
  const float* xbase = x + (size_t)tb * 524288 + (size_t)nc * 64 * 512 + cc * 64;
  bf16* xbb = xb + (size_t)tb * 524288 + (size_t)nc * 64 * 512 + cc * 64;
  bf16* xTb = xT + (size_t)tb * 524288 + (size_t)(cc * 64) * 1024 + nc * 64;
  const int rgrp = t >> 4, k = t & 15;
  float s0 = 0, s1 = 0, s2 = 0, s3 = 0;
#pragma unroll
  for (int p = 0; p < 4; p++) {
    int r = p * 16 + rgrp;
    float4 v = *(const float4*)(xbase + (size_t)r * 512 + k * 4);
    bf16x4 o; o[0]=(bf16)v.x; o[1]=(bf16)v.y; o[2]=(bf16)v.z; o[3]=(bf16)v.w;
    *(bf16x4*)(xbb + (size_t)r * 512 + k * 4) = o;
    lds[r][k*4+0]=v.x; lds[r][k*4+1]=v.y; lds[r][k*4+2]=v.z; lds[r][k*4+3]=v.w;
    s0 += v.x; s1 += v.y; s2 += v.z; s3 += v.w;
  }
  sred[rgrp][k*4+0]=s0; sred[rgrp][k*4+1]=s1; sred[rgrp][k*4+2]=s2; sred[rgrp][k*4+3]=s3;
  __syncthreads();
#pragma unroll
  for (int p = 0; p < 16; p++) {
    int c = p * 4 + (t >> 6), n = t & 63;
    xTb[(size_t)c * 1024 + n] = (bf16)lds[n][c];
  }
  if (t < 64) {
    float tot = 0;
#pragma unroll
    for (int rg = 0; rg < 16; rg++) tot += sred[rg][t];
    spart[(size_t)((tb*8 + cc)*16 + nc) * 64 + t] = tot;
  }
}

// ---- ksv[m][tb][d] = sum_c W'[m][d,c] * s[tb][c] ----
__global__ __launch_bounds__(512)
void ksvs(const bf16* __restrict__ WB, const float* __restrict__ spart,
          float* __restrict__ ksv) {
  const int tb = blockIdx.x, m = blockIdx.y;
  const int c = threadIdx.x, cc = c >> 6, cl = c & 63;
  __shared__ float sl[512];
  float tot = 0;
#pragma unroll
  for (int ncf = 0; ncf < 16; ncf++)
    tot += spart[(size_t)((tb*8 + cc)*16 + ncf) * 64 + cl];
  sl[c] = tot;
  __syncthreads();
  const bf16* Wrow = WB + (size_t)(m + 1) * 262144 + (size_t)c * 512;
  float acc = 0;
  for (int k = 0; k < 512; k += 8) {
    bf16x8 wv = *(const bf16x8*)(Wrow + k);
#pragma unroll
    for (int i = 0; i < 8; i++) acc += (float)wv[i] * sl[k + i];
  }
  ksv[m * 16384 + tb * 512 + c] = acc;
}

// =====================================================================
// Batched 128x128 bf16 GEMM, BK=64, single-buffered 32KB LDS (4 blk/CU),
// chunk-XOR swizzle, gload_lds staging, XCD-clustered batches.
// Epilogue: LDS-bounce -> coalesced bf16x8 stores.
// SYM: triangular tiles; off-diag also stores transposed tile.
// =====================================================================
template <int NKT, int MT, int NT, bool SYM>
__global__ __launch_bounds__(256)
void gemm_b(const bf16* __restrict__ Abase, size_t Astr,
            const bf16* __restrict__ Btbase, size_t Btstr,
            bf16* __restrict__ ob, size_t Ostr) {
  constexpr int K = NKT * 64;
  constexpr int PERB = SYM ? (MT * (MT + 1) / 2) : (MT * NT);
  const int bid = blockIdx.x;
  const int xcd = bid & 7, j9 = bid >> 3;
  const int bat = xcd + 8 * (j9 / PERB);
  const int tile = j9 % PERB;
  int mi, ni;
  if constexpr (SYM) {
    if (tile < 4)      { mi = 0; ni = tile; }
    else if (tile < 7) { mi = 1; ni = tile - 3; }
    else if (tile < 9) { mi = 2; ni = tile - 5; }
    else               { mi = 3; ni = 3; }
  } else { mi = tile / NT; ni = tile % NT; }
  const bf16* A = Abase + (size_t)bat * Astr;
  const bf16* Bt = Btbase + (size_t)bat * Btstr;
  const int m0 = mi * 128, n0 = ni * 128;
  __shared__ __align__(16) char smem[32768];
  bf16* As = (bf16*)smem;              // [128][64]
  bf16* Bs = (bf16*)(smem + 16384);    // [128][64]
  const int tid = threadIdx.x, w = tid >> 6, l = tid & 63;
  const int wm = w >> 1, wn = w & 1;
  const int lr = l & 15, lq = l >> 4, l7 = l & 7, lh = l >> 3;
  const int srcc = (l7 ^ lh) * 8;
  f32x4 acc[4][4] = {};
  for (int kt = 0; kt < NKT; kt++) {
#pragma unroll
    for (int i = 0; i < 4; i++) {
      int rb = w * 32 + i * 8;
      gload16(A  + (size_t)(m0 + rb + lh) * K + kt * 64 + srcc, &As[rb * 64]);
      gload16(Bt + (size_t)(n0 + rb + lh) * K + kt * 64 + srcc, &Bs[rb * 64]);
    }
    __syncthreads();
    bf16x8 af[4][2], bv[4][2];
#pragma unroll
    for (int f = 0; f < 4; f++) {
      int ra = wm * 64 + f * 16 + lr, rb2 = wn * 64 + f * 16 + lr;
#pragma unroll
      for (int s = 0; s < 2; s++) {
        af[f][s] = *(const bf16x8*)&As[ra * 64 + (((s*4+lq) ^ (ra & 7)) * 8)];
        bv[f][s] = *(const bf16x8*)&Bs[rb2 * 64 + (((s*4+lq) ^ (rb2 & 7)) * 8)];
      }
    }
#pragma unroll
    for (int mt = 0; mt < 4; mt++)
#pragma unroll
      for (int nt = 0; nt < 4; nt++)
#pragma unroll
        for (int s = 0; s < 2; s++)
          acc[mt][nt] = __builtin_amdgcn_mfma_f32_16x16x32_bf16(
              af[mt][s], bv[nt][s], acc[mt][nt], 0, 0, 0);
    __syncthreads();
  }

  const int ldo = NT * 128;
  bf16* TB = (bf16*)smem;   // [128][128] bf16 = 32 KB (safe: loop ended with sync)
#pragma unroll
  for (int mt = 0; mt < 4; mt++)
#pragma unroll
    for (int nt = 0; nt < 4; nt++) {
      int col = wn * 64 + nt * 16 + lr;
#pragma unroll
      for (int r = 0; r < 4; r++) {
        int cr = wm * 64 + mt * 16 + lq * 4 + r;
        TB[cr * 128 + col] = (bf16)acc[mt][nt][r];
      }
    }
  __syncthreads();
#pragma unroll
  for (int rd = 0; rd < 8; rd++) {
    int row = rd * 16 + (tid >> 4);
    int ch = tid & 15;
    bf16x8 v = *(const bf16x8*)&TB[row * 128 + ch * 8];
    *(bf16x8*)(ob + (size_t)bat * Ostr + (size_t)(m0 + row) * ldo + n0 + ch * 8) = v;
  }

  if constexpr (SYM) {
    if (mi != ni) {
      __syncthreads();
#pragma unroll
      for (int mt = 0; mt < 4; mt++)
#pragma unroll
        for (int nt = 0; nt < 4; nt++) {
          int a = wn * 64 + nt * 16 + lr;
#pragma unroll
          for (int r = 0; r < 4; r++) {
            int b = wm * 64 + mt * 16 + lq * 4 + r;
            TB[(a * 128 + b) ^ ((a & 7) << 3)] = (bf16)acc[mt][nt][r];
          }
        }
      __syncthreads();
      const int rowa = tid >> 1, half = tid & 1;
#pragma unroll
      for (int i = 0; i < 8; i++) {
        int c8 = half * 8 + i;
        bf16x8 v = *(const bf16x8*)&TB[(rowa * 128 + c8 * 8) ^ ((rowa & 7) << 3)];
        *(bf16x8*)(ob + (size_t)bat * Ostr + (size_t)(ni * 128 + rowa) * ldo +
                   mi * 128 + c8 * 8) = v;
      }
    }
  }
}

// =====================================================================
// Out-GEMM: 128x128 tile, K=512, f32 out + bias (bp' + sum_h cpart),
// LDS-bounce epilogue (2 passes of 64x132 f32) -> float4 stores.
// =====================================================================
__global__ __launch_bounds__(256)
void gemm_o(const bf16* __restrict__ Abase, const bf16* __restrict__ Btbase,
            const float* __restrict__ BSb, const float* __restrict__ cpart,
            float* __restrict__ of) {
  constexpr int K = 512, NKT = 8, PERB = 32;   // 8 m-tiles x 4 n-tiles
  const int bid = blockIdx.x;
  const int xcd = bid & 7, j9 = bid >> 3;
  const int bat = xcd + 8 * (j9 / PERB);
  const int tile = j9 % PERB;
  const int mi = tile >> 2, ni = tile & 3;
  const bf16* A = Abase + (size_t)bat * 524288;
  const bf16* Bt = Btbase + (size_t)bat * 262144;
  const int m0 = mi * 128, n0 = ni * 128;
  __shared__ __align__(16) char smem[33792];   // max(As+Bs=32K, TB=64*132*4)
  bf16* As = (bf16*)smem;
  bf16* Bs = (bf16*)(smem + 16384);
  const int tid = threadIdx.x, w = tid >> 6, l = tid & 63;
  const int wm = w >> 1, wn = w & 1;
  const int lr = l & 15, lq = l >> 4, l7 = l & 7, lh = l >> 3;
  const int srcc = (l7 ^ lh) * 8;
  f32x4 acc[4][4] = {};
  for (int kt = 0; kt < NKT; kt++) {
#pragma unroll
    for (int i = 0; i < 4; i++) {
      int rb = w * 32 + i * 8;
      gload16(A  + (size_t)(m0 + rb + lh) * K + kt * 64 + srcc, &As[rb * 64]);
      gload16(Bt + (size_t)(n0 + rb + lh) * K + kt * 64 + srcc, &Bs[rb * 64]);
    }
    __syncthreads();
    bf16x8 af[4][2], bv[4][2];
#pragma unroll
    for (int f = 0; f < 4; f++) {
      int ra = wm * 64 + f * 16 + lr, rb2 = wn * 64 + f * 16 + lr;
#pragma unroll
      for (int s = 0; s < 2; s++) {
        af[f][s] = *(const bf16x8*)&As[ra * 64 + (((s*4+lq) ^ (ra & 7)) * 8)];
        bv[f][s] = *(const bf16x8*)&Bs[rb2 * 64 + (((s*4+lq) ^ (rb2 & 7)) * 8)];
      }
    }
#pragma unroll
    for (int mt = 0; mt < 4; mt++)
#pragma unroll
      for (int nt = 0; nt < 4; nt++)
#pragma unroll
        for (int s = 0; s < 2; s++)
          acc[mt][nt] = __builtin_amdgcn_mfma_f32_16x16x32_bf16(
              af[mt][s], bv[nt][s], acc[mt][nt], 0, 0, 0);
    __syncthreads();
  }

  // hoisted bias
  float bja[4];
#pragma unroll
  for (int nt = 0; nt < 4; nt++) {
    int j = n0 + wn * 64 + nt * 16 + lr;
    float bj = BSb[1536 + j];
#pragma unroll
    for (int h = 0; h < 8; h++)
      bj += cpart[(size_t)(bat * 8 + h) * 512 + j];
    bja[nt] = bj;
  }

  float* TB = (float*)smem;   // [64][132]
#pragma unroll
  for (int p = 0; p < 2; p++) {
    if (p) __syncthreads();
#pragma unroll
    for (int mtl = 0; mtl < 2; mtl++) {
      int mt = 2 * p + mtl;
#pragma unroll
      for (int nt = 0; nt < 4; nt++) {
        int col = wn * 64 + nt * 16 + lr;
#pragma unroll
        for (int r = 0; r < 4; r++) {
          int cr = wm * 32 + mtl * 16 + lq * 4 + r;
          TB[cr * 132 + col] = acc[mt][nt][r] + bja[nt];
        }
      }
    }
    __syncthreads();
#pragma unroll
    for (int rd = 0; rd < 8; rd++) {
      int row = rd * 8 + (tid >> 5);
      int cf = (tid & 31) * 4;
      float4 v = *(const float4*)&TB[row * 132 + cf];
      int wm_g = row >> 5, within = row & 31;
      int grow = m0 + wm_g * 64 + p * 32 + within;
      *(float4*)&of[(size_t)bat * 524288 + (size_t)grow * 512 + n0 + cf] = v;
    }
  }
}

// =====================================================================
// kvz: per (tb,h): kv = (KG_h V_h^T + rank-1)/N + bk bv^T; Z_h = kv P_h^T
// =====================================================================
__global__ __launch_bounds__(256)
void kvz(const bf16* __restrict__ KGb, const bf16* __restrict__ WB,
         const float* __restrict__ BS, const float* __restrict__ ksv,
         bf16* __restrict__ ZT, float* __restrict__ cpart) {
  const int gid = blockIdx.x, tb = gid >> 3, h = gid & 7;
  const int t = threadIdx.x, w = t >> 6, l = t & 63;
  const int lr = l & 15, lq = l >> 4;
  __shared__ __align__(16) char lds[65536 + 65536 + 8192];
  bf16* bufA = (bf16*)lds;
  bf16* bufV = (bf16*)(lds + 65536);
  bf16* kvb  = (bf16*)(lds + 131072);

#pragma unroll
  for (int i = 0; i < 16; i++) {
    int r = i * 4 + w;
    gload16(KGb + (size_t)tb * 262144 + (size_t)(64*h + r) * 512 + ((l ^ (r & 7)) * 8),
            bufA + r * 512);
    gload16(WB + 2u * 262144 + (size_t)(64*h + r) * 512 + ((l ^ (r & 7)) * 8),
            bufV + r * 512);
  }
  __syncthreads();

  f32x4 acc2[4][4] = {};
#pragma unroll
  for (int ks = 0; ks < 4; ks++) {
    int gch = w * 16 + ks * 4 + lq;
    bf16x8 af2[4], bv2[4];
#pragma unroll
    for (int mf = 0; mf < 4; mf++) {
      int d = mf * 16 + lr;
      af2[mf] = *(const bf16x8*)&bufA[d * 512 + ((gch ^ (d & 7)) * 8)];
    }
#pragma unroll
    for (int nf = 0; nf < 4; nf++) {
      int e = nf * 16 + lr;
      bv2[nf] = *(const bf16x8*)&bufV[e * 512 + ((gch ^ (e & 7)) * 8)];
    }
#pragma unroll
    for (int mf = 0; mf < 4; mf++)
#pragma unroll
      for (int nf = 0; nf < 4; nf++)
        acc2[mf][nf] = __builtin_amdgcn_mfma_f32_16x16x32_bf16(
            af2[mf], bv2[nf], acc2[mf][nf], 0, 0, 0);
  }
  __syncthreads();

  float* part = (float*)lds + w * 4096;
#pragma unroll
  for (int mf = 0; mf < 4; mf++)
#pragma unroll
    for (int nf = 0; nf < 4; nf++)
#pragma unroll
      for (int r = 0; r < 4; r++) {
        int d = mf * 16 + lq * 4 + r, e = nf * 16 + lr;
        part[d * 64 + e] = acc2[mf][nf][r];
      }
  __syncthreads();
  {
    const float inv = 1.f / 1024.f;
    const float* pb = (const float*)lds;
#pragma unroll
    for (int jj = 0; jj < 16; jj++) {
      int flat = jj * 256 + t, d = flat >> 6, e = flat & 63;
      float s = pb[flat] + pb[4096 + flat] + pb[8192 + flat] + pb[12288 + flat];
      float ksh = ksv[tb * 512 + 64*h + d];
      float vsh = ksv[16384 + tb * 512 + 64*h + e];
      float bkh = BS[512 + 64*h + d];
      float bvh = BS[1024 + 64*h + e];
      float kv = (s + ksh * bvh + bkh * vsh) * inv + bkh * bvh;
      kvb[d * 64 + (((e >> 3) ^ (d & 7)) * 8 + (e & 7))] = (bf16)kv;
    }
  }
  __syncthreads();

#pragma unroll
  for (int i = 0; i < 16; i++) {
    int rb = i * 32 + w * 8;
    int r = rb + (l >> 3);
    gload16(WB + 3u * 262144 + (size_t)r * 512 + 64*h + (((l & 7) ^ (r & 7)) * 8),
            bufA + rb * 64);
  }
  __syncthreads();

  f32x4 acc3[4][8] = {};
#pragma unroll
  for (int s = 0; s < 2; s++) {
    bf16x8 af3[4];
#pragma unroll
    for (int mf = 0; mf < 4; mf++) {
      int d = mf * 16 + lr;
      af3[mf] = *(const bf16x8*)&kvb[d * 64 + (((s*4+lq) ^ (d & 7)) * 8)];
    }
#pragma unroll
    for (int nf = 0; nf < 8; nf++) {
      int jj = w * 128 + nf * 16 + lr;
      bf16x8 b3 = *(const bf16x8*)&bufA[jj * 64 + (((s*4+lq) ^ (jj & 7)) * 8)];
#pragma unroll
      for (int mf = 0; mf < 4; mf++)
        acc3[mf][nf] = __builtin_amdgcn_mfma_f32_16x16x32_bf16(
            af3[mf], b3, acc3[mf][nf], 0, 0, 0);
    }
  }

  bf16* zbase = ZT + (size_t)tb * 262144 + 64*h;
#pragma unroll
  for (int nf = 0; nf < 8; nf++) {
    int jj = w * 128 + nf * 16 + lr;
    float cp = 0.f;
#pragma unroll
    for (int mf = 0; mf < 4; mf++) {
      bf16x4 o;
#pragma unroll
      for (int r = 0; r < 4; r++) {
        o[r] = (bf16)acc3[mf][nf][r];
        cp += acc3[mf][nf][r] * BS[64*h + mf*16 + lq*4 + r];
      }
      *(bf16x4*)(zbase + (size_t)jj * 512 + mf * 16 + lq * 4) = o;
    }
    cp += __shfl_xor(cp, 16);
    cp += __shfl_xor(cp, 32);
    if (lq == 0) cpart[(size_t)(tb * 8 + h) * 512 + jj] = cp;
  }
}

extern "C" void kernel_launch(void* const* d_in, const int* in_sizes, int n_in,
                              void* d_out, int out_size, void* d_ws, size_t ws_size,
                              hipStream_t stream) {
  const float* x = (const float*)d_in[0];
  char* ws = (char*)d_ws;
  bf16*  xb    = (bf16*)(ws + 0);             // [32][1024][512]
  bf16*  xT    = (bf16*)(ws + 33554432);      // [32][512][1024]
  bf16*  Gb    = (bf16*)(ws + 67108864);      // [32][512][512]
  bf16*  KGb   = (bf16*)(ws + 83886080);      // [32][512][512]
  bf16*  ZT    = (bf16*)(ws + 100663296);     // [32][512][512]
  bf16*  VT    = (bf16*)(ws + 117440512);     // [32][512][512]
  bf16*  WB    = (bf16*)(ws + 134217728);     // [4][512][512]
  bf16*  WqT   = (bf16*)(ws + 136314880);     // [512][512]
  float* BS    = (float*)(ws + 136839168);    // [4][512]
  float* ksv   = (float*)(ws + 136847360);    // [2][32][512]
  float* cpart = (float*)(ws + 136978432);    // [32][8][512]
  float* spart = (float*)(ws + 137502720);    // [32*8*16][64]
  (void)in_sizes; (void)n_in; (void)out_size; (void)ws_size;

  PtrPack pk;
  for (int i = 0; i < 24; i++) pk.p[i] = (const float*)d_in[1 + i];

  prep_all<<<2048, 256, 0, stream>>>(pk, WB, BS);
  prep_wqT<<<64, 256, 0, stream>>>((const float*)d_in[1], (const float*)d_in[3],
                                   (const float*)d_in[6], WqT);
  cvt_x_t<<<4096, 256, 0, stream>>>(x, xb, xT, spart);
  ksvs<<<dim3(32, 2), 512, 0, stream>>>(WB, spart, ksv);
  // Gram: G[tb] = xT[tb] * xT[tb]^T  (symmetric)
  gemm_b<16, 4, 4, true><<<320, 256, 0, stream>>>(
      xT, 524288, xT, 524288, Gb, 262144);
  // KG[tb] = K' * G[tb]
  gemm_b<8, 4, 4, false><<<512, 256, 0, stream>>>(
      WB + 262144, 0, Gb, 262144, KGb, 262144);
  kvz<<<256, 256, 0, stream>>>(KGb, WB, BS, ksv, ZT, cpart);
  // VT[tb] = ZT[tb] * WqT^T
  gemm_b<8, 4, 4, false><<<512, 256, 0, stream>>>(
      ZT, 262144, WqT, 0, VT, 262144);
  // out[tb] = xb[tb] * VT[tb]^T + (bp' + sum_h cpart)
  gemm_o<<<1024, 256, 0, stream>>>(xb, VT, BS, cpart, (float*)d_out);
}

// Round 8
// 144.153 us; speedup vs baseline: 1.0849x; 1.0849x over previous
//
#include <hip/hip_runtime.h>

#define T_ 4
#define B_ 8
#define N_ 1024
#define C_ 512
#define H_ 8
#define D_ 64
#define M_ (T_*B_*N_)   // 32768 rows
#define TB_ (T_*B_)     // 32

typedef __bf16 bf16;
typedef __bf16 bf16x4 __attribute__((ext_vector_type(4)));
typedef __bf16 bf16x8 __attribute__((ext_vector_type(8)));
typedef float f32x4 __attribute__((ext_vector_type(4)));

__device__ __forceinline__ void gload16(const void* g, void* l) {
  __builtin_amdgcn_global_load_lds(
      (const __attribute__((address_space(1))) void*)g,
      (__attribute__((address_space(3))) void*)l, 16, 0, 0);
}

struct PtrPack { const float* p[24]; };

// ---- fold BN into weights for all 4 mats ----
__global__ __launch_bounds__(256)
void prep_all(PtrPack pk, bf16* __restrict__ WB, float* __restrict__ BS) {
  const int mat = blockIdx.x >> 9, d = blockIdx.x & 511;
  const float* W    = pk.p[6*mat + 0];
  const float* b    = pk.p[6*mat + 1];
  const float* g    = pk.p[6*mat + 2];
  const float* beta = pk.p[6*mat + 3];
  const float* mu   = pk.p[6*mat + 4];
  const float* var  = pk.p[6*mat + 5];
  float s = g[d] * rsqrtf(var[d] + 1e-5f);
  if (threadIdx.x == 0) BS[mat*512 + d] = (b[d] - mu[d]) * s + beta[d];
  bf16* Wout = WB + (size_t)mat * 262144 + (size_t)d * 512;
  for (int c = threadIdx.x; c < 512; c += 256)
    Wout[c] = (bf16)(W[(size_t)d * 512 + c] * s);
}

// ---- WqT[c][d] = Wq[d][c] * sq[d] ----
__global__ __launch_bounds__(256)
void prep_wqT(const float* __restrict__ W, const float* __restrict__ g,
              const float* __restrict__ var, bf16* __restrict__ WqT) {
  const int di = blockIdx.x >> 3, ci = blockIdx.x & 7;
  const int t = threadIdx.x;
  __shared__ float lds[64][65];
  const int rgrp = t >> 4, k = t & 15;
#pragma unroll
  for (int p = 0; p < 4; p++) {
    int r = p * 16 + rgrp;
    int d = di * 64 + r;
    float s = g[d] * rsqrtf(var[d] + 1e-5f);
    float4 v = *(const float4*)(W + (size_t)d * 512 + ci * 64 + k * 4);
    lds[r][k*4+0] = v.x * s; lds[r][k*4+1] = v.y * s;
    lds[r][k*4+2] = v.z * s; lds[r][k*4+3] = v.w * s;
  }
  __syncthreads();
#pragma unroll
  for (int p = 0; p < 16; p++) {
    int c = p * 4 + (t >> 6), dd = t & 63;
    WqT[(size_t)(ci*64 + c) * 512 + di*64 + dd] = (bf16)lds[dd][c];
  }
}

// ---- x -> xb + xT + col-sum partials ----
__global__ __launch_bounds__(256)
void cvt_x_t(const float* __restrict__ x, bf16* __restrict__ xb,
             bf16* __restrict__ xT, float* __restrict__ spart) {
  const int bid = blockIdx.x;
  const int tb = bid >> 7, nc = (bid >> 3) & 15, cc = bid & 7;
  const int t = threadIdx.x;
  __shared__ float lds[64][65];
  __shared__ float sred[16][64];
  const float* xbase = x + (size_t)tb * 524288 + (size_t)nc * 64 * 512 + cc * 64;
  bf16* xbb = xb + (size_t)tb * 524288 + (size_t)nc * 64 * 512 + cc * 64;
  bf16* xTb = xT + (size_t)tb * 524288 + (size_t)(cc * 64) * 1024 + nc * 64;
  const int rgrp = t >> 4, k = t & 15;
  float s0 = 0, s1 = 0, s2 = 0, s3 = 0;
#pragma unroll
  for (int p = 0; p < 4; p++) {
    int r = p * 16 + rgrp;
    float4 v = *(const float4*)(xbase + (size_t)r * 512 + k * 4);
    bf16x4 o; o[0]=(bf16)v.x; o[1]=(bf16)v.y; o[2]=(bf16)v.z; o[3]=(bf16)v.w;
    *(bf16x4*)(xbb + (size_t)r * 512 + k * 4) = o;
    lds[r][k*4+0]=v.x; lds[r][k*4+1]=v.y; lds[r][k*4+2]=v.z; lds[r][k*4+3]=v.w;
    s0 += v.x; s1 += v.y; s2 += v.z; s3 += v.w;
  }
  sred[rgrp][k*4+0]=s0; sred[rgrp][k*4+1]=s1; sred[rgrp][k*4+2]=s2; sred[rgrp][k*4+3]=s3;
  __syncthreads();
#pragma unroll
  for (int p = 0; p < 16; p++) {
    int c = p * 4 + (t >> 6), n = t & 63;
    xTb[(size_t)c * 1024 + n] = (bf16)lds[n][c];
  }
  if (t < 64) {
    float tot = 0;
#pragma unroll
    for (int rg = 0; rg < 16; rg++) tot += sred[rg][t];
    spart[(size_t)((tb*8 + cc)*16 + nc) * 64 + t] = tot;
  }
}

// ---- ksv[m][tb][d] = sum_c W'[m][d,c] * s[tb][c] ----
__global__ __launch_bounds__(512)
void ksvs(const bf16* __restrict__ WB, const float* __restrict__ spart,
          float* __restrict__ ksv) {
  const int tb = blockIdx.x, m = blockIdx.y;
  const int c = threadIdx.x, cc = c >> 6, cl = c & 63;
  __shared__ float sl[512];
  float tot = 0;
#pragma unroll
  for (int ncf = 0; ncf < 16; ncf++)
    tot += spart[(size_t)((tb*8 + cc)*16 + ncf) * 64 + cl];
  sl[c] = tot;
  __syncthreads();
  const bf16* Wrow = WB + (size_t)(m + 1) * 262144 + (size_t)c * 512;
  float acc = 0;
  for (int k = 0; k < 512; k += 8) {
    bf16x8 wv = *(const bf16x8*)(Wrow + k);
#pragma unroll
    for (int i = 0; i < 8; i++) acc += (float)wv[i] * sl[k + i];
  }
  ksv[m * 16384 + tb * 512 + c] = acc;
}

// =====================================================================
// Batched 64x128-tile GEMM (N fixed 512 -> 4 n-tiles), BK=64, 24 KB LDS
// single-buffered -> 5-6 blocks/CU, chunk-XOR swizzle, gload_lds staging,
// XCD-clustered batches.  C[m][j] = sum_k A[m,k]*Bt[j,k].
// Inner loop verbatim from the verified 128^2 kernel; only tile map shrunk.
// =====================================================================
template <int NKT, int MTILES, bool BF16OUT, bool BIAS>
__global__ __launch_bounds__(256)
void gemm_n(const bf16* __restrict__ Abase, size_t Astr,
            const bf16* __restrict__ Btbase, size_t Btstr,
            const float* __restrict__ BSb, const float* __restrict__ cpart,
            bf16* __restrict__ ob, float* __restrict__ of, size_t Ostr) {
  constexpr int K = NKT * 64;
  constexpr int PERB = MTILES * 4;
  const int bid = blockIdx.x;
  const int xcd = bid & 7, j9 = bid >> 3;
  const int bat = xcd + 8 * (j9 / PERB);
  const int tile = j9 % PERB;
  const int mi = tile >> 2, ni = tile & 3;
  const bf16* A = Abase + (size_t)bat * Astr;
  const bf16* Bt = Btbase + (size_t)bat * Btstr;
  const int m0 = mi * 64, n0 = ni * 128;
  __shared__ __align__(16) bf16 As[64][64];    //  8 KB
  __shared__ __align__(16) bf16 Bs[128][64];   // 16 KB
  const int tid = threadIdx.x, w = tid >> 6, l = tid & 63;
  const int wm = w >> 1, wn = w & 1;
  const int lr = l & 15, lq = l >> 4, l7 = l & 7, lh = l >> 3;
  const int srcc = (l7 ^ lh) * 8;
  f32x4 acc[2][4] = {};
  for (int kt = 0; kt < NKT; kt++) {
#pragma unroll
    for (int i = 0; i < 2; i++) {              // A: 8 chunks of 8 rows
      int rb = w * 16 + i * 8;
      gload16(A + (size_t)(m0 + rb + lh) * K + kt * 64 + srcc, &As[rb][0]);
    }
#pragma unroll
    for (int i = 0; i < 4; i++) {              // B: 16 chunks of 8 rows
      int rb = w * 32 + i * 8;
      gload16(Bt + (size_t)(n0 + rb + lh) * K + kt * 64 + srcc, &Bs[rb][0]);
    }
    __syncthreads();
    bf16x8 af[2][2], bv[4][2];
#pragma unroll
    for (int f = 0; f < 2; f++) {
      int ra = wm * 32 + f * 16 + lr;
#pragma unroll
      for (int s = 0; s < 2; s++)
        af[f][s] = *(const bf16x8*)&As[ra][((s*4+lq) ^ (ra & 7)) * 8];
    }
#pragma unroll
    for (int f = 0; f < 4; f++) {
      int rb2 = wn * 64 + f * 16 + lr;
#pragma unroll
      for (int s = 0; s < 2; s++)
        bv[f][s] = *(const bf16x8*)&Bs[rb2][((s*4+lq) ^ (rb2 & 7)) * 8];
    }
#pragma unroll
    for (int mt = 0; mt < 2; mt++)
#pragma unroll
      for (int nt = 0; nt < 4; nt++)
#pragma unroll
        for (int s = 0; s < 2; s++)
          acc[mt][nt] = __builtin_amdgcn_mfma_f32_16x16x32_bf16(
              af[mt][s], bv[nt][s], acc[mt][nt], 0, 0, 0);
    __syncthreads();
  }

  float bja[4];
  if constexpr (BIAS) {
#pragma unroll
    for (int nt = 0; nt < 4; nt++) {
      int j = n0 + wn * 64 + nt * 16 + lr;
      float bj = BSb[1536 + j];
#pragma unroll
      for (int h = 0; h < 8; h++)
        bj += cpart[(size_t)(bat * 8 + h) * 512 + j];
      bja[nt] = bj;
    }
  }
#pragma unroll
  for (int mt = 0; mt < 2; mt++)
#pragma unroll
    for (int nt = 0; nt < 4; nt++) {
      int j = n0 + wn * 64 + nt * 16 + lr;
      size_t mrow = (size_t)m0 + wm * 32 + mt * 16 + lq * 4;
#pragma unroll
      for (int r = 0; r < 4; r++) {
        if constexpr (BF16OUT)
          ob[(size_t)bat * Ostr + (mrow + r) * 512 + j] = (bf16)acc[mt][nt][r];
        else
          of[(size_t)bat * Ostr + (mrow + r) * 512 + j] =
              acc[mt][nt][r] + (BIAS ? bja[nt] : 0.f);
      }
    }
}

// =====================================================================
// kvz: per (tb,h): kv = (KG_h V_h^T + rank-1)/N + bk bv^T; Z_h = kv P_h^T
// =====================================================================
__global__ __launch_bounds__(256)
void kvz(const bf16* __restrict__ KGb, const bf16* __restrict__ WB,
         const float* __restrict__ BS, const float* __restrict__ ksv,
         bf16* __restrict__ ZT, float* __restrict__ cpart) {
  const int gid = blockIdx.x, tb = gid >> 3, h = gid & 7;
  const int t = threadIdx.x, w = t >> 6, l = t & 63;
  const int lr = l & 15, lq = l >> 4;
  __shared__ __align__(16) char lds[65536 + 65536 + 8192];
  bf16* bufA = (bf16*)lds;
  bf16* bufV = (bf16*)(lds + 65536);
  bf16* kvb  = (bf16*)(lds + 131072);

#pragma unroll
  for (int i = 0; i < 16; i++) {
    int r = i * 4 + w;
    gload16(KGb + (size_t)tb * 262144 + (size_t)(64*h + r) * 512 + ((l ^ (r & 7)) * 8),
            bufA + r * 512);
    gload16(WB + 2u * 262144 + (size_t)(64*h + r) * 512 + ((l ^ (r & 7)) * 8),
            bufV + r * 512);
  }
  __syncthreads();

  f32x4 acc2[4][4] = {};
#pragma unroll
  for (int ks = 0; ks < 4; ks++) {
    int gch = w * 16 + ks * 4 + lq;
    bf16x8 af2[4], bv2[4];
#pragma unroll
    for (int mf = 0; mf < 4; mf++) {
      int d = mf * 16 + lr;
      af2[mf] = *(const bf16x8*)&bufA[d * 512 + ((gch ^ (d & 7)) * 8)];
    }
#pragma unroll
    for (int nf = 0; nf < 4; nf++) {
      int e = nf * 16 + lr;
      bv2[nf] = *(const bf16x8*)&bufV[e * 512 + ((gch ^ (e & 7)) * 8)];
    }
#pragma unroll
    for (int mf = 0; mf < 4; mf++)
#pragma unroll
      for (int nf = 0; nf < 4; nf++)
        acc2[mf][nf] = __builtin_amdgcn_mfma_f32_16x16x32_bf16(
            af2[mf], bv2[nf], acc2[mf][nf], 0, 0, 0);
  }
  __syncthreads();

  float* part = (float*)lds + w * 4096;
#pragma unroll
  for (int mf = 0; mf < 4; mf++)
#pragma unroll
    for (int nf = 0; nf < 4; nf++)
#pragma unroll
      for (int r = 0; r < 4; r++) {
        int d = mf * 16 + lq * 4 + r, e = nf * 16 + lr;
        part[d * 64 + e] = acc2[mf][nf][r];
      }
  __syncthreads();
  {
    const float inv = 1.f / 1024.f;
    const float* pb = (const float*)lds;
#pragma unroll
    for (int jj = 0; jj < 16; jj++) {
      int flat = jj * 256 + t, d = flat >> 6, e = flat & 63;
      float s = pb[flat] + pb[4096 + flat] + pb[8192 + flat] + pb[12288 + flat];
      float ksh = ksv[tb * 512 + 64*h + d];
      float vsh = ksv[16384 + tb * 512 + 64*h + e];
      float bkh = BS[512 + 64*h + d];
      float bvh = BS[1024 + 64*h + e];
      float kv = (s + ksh * bvh + bkh * vsh) * inv + bkh * bvh;
      kvb[d * 64 + (((e >> 3) ^ (d & 7)) * 8 + (e & 7))] = (bf16)kv;
    }
  }
  __syncthreads();

#pragma unroll
  for (int i = 0; i < 16; i++) {
    int rb = i * 32 + w * 8;
    int r = rb + (l >> 3);
    gload16(WB + 3u * 262144 + (size_t)r * 512 + 64*h + (((l & 7) ^ (r & 7)) * 8),
            bufA + rb * 64);
  }
  __syncthreads();

  f32x4 acc3[4][8] = {};
#pragma unroll
  for (int s = 0; s < 2; s++) {
    bf16x8 af3[4];
#pragma unroll
    for (int mf = 0; mf < 4; mf++) {
      int d = mf * 16 + lr;
      af3[mf] = *(const bf16x8*)&kvb[d * 64 + (((s*4+lq) ^ (d & 7)) * 8)];
    }
#pragma unroll
    for (int nf = 0; nf < 8; nf++) {
      int jj = w * 128 + nf * 16 + lr;
      bf16x8 b3 = *(const bf16x8*)&bufA[jj * 64 + (((s*4+lq) ^ (jj & 7)) * 8)];
#pragma unroll
      for (int mf = 0; mf < 4; mf++)
        acc3[mf][nf] = __builtin_amdgcn_mfma_f32_16x16x32_bf16(
            af3[mf], b3, acc3[mf][nf], 0, 0, 0);
    }
  }

  bf16* zbase = ZT + (size_t)tb * 262144 + 64*h;
#pragma unroll
  for (int nf = 0; nf < 8; nf++) {
    int jj = w * 128 + nf * 16 + lr;
    float cp = 0.f;
#pragma unroll
    for (int mf = 0; mf < 4; mf++) {
      bf16x4 o;
#pragma unroll
      for (int r = 0; r < 4; r++) {
        o[r] = (bf16)acc3[mf][nf][r];
        cp += acc3[mf][nf][r] * BS[64*h + mf*16 + lq*4 + r];
      }
      *(bf16x4*)(zbase + (size_t)jj * 512 + mf * 16 + lq * 4) = o;
    }
    cp += __shfl_xor(cp, 16);
    cp += __shfl_xor(cp, 32);
    if (lq == 0) cpart[(size_t)(tb * 8 + h) * 512 + jj] = cp;
  }
}

extern "C" void kernel_launch(void* const* d_in, const int* in_sizes, int n_in,
                              void* d_out, int out_size, void* d_ws, size_t ws_size,
                              hipStream_t stream) {
  const float* x = (const float*)d_in[0];
  char* ws = (char*)d_ws;
  bf16*  xb    = (bf16*)(ws + 0);             // [32][1024][512]
  bf16*  xT    = (bf16*)(ws + 33554432);      // [32][512][1024]
  bf16*  Gb    = (bf16*)(ws + 67108864);      // [32][512][512]
  bf16*  KGb   = (bf16*)(ws + 83886080);      // [32][512][512]
  bf16*  ZT    = (bf16*)(ws + 100663296);     // [32][512][512]
  bf16*  VT    = (bf16*)(ws + 117440512);     // [32][512][512]
  bf16*  WB    = (bf16*)(ws + 134217728);     // [4][512][512]
  bf16*  WqT   = (bf16*)(ws + 136314880);     // [512][512]
  float* BS    = (float*)(ws + 136839168);    // [4][512]
  float* ksv   = (float*)(ws + 136847360);    // [2][32][512]
  float* cpart = (float*)(ws + 136978432);    // [32][8][512]
  float* spart = (float*)(ws + 137502720);    // [32*8*16][64]
  (void)in_sizes; (void)n_in; (void)out_size; (void)ws_size;

  PtrPack pk;
  for (int i = 0; i < 24; i++) pk.p[i] = (const float*)d_in[1 + i];

  prep_all<<<2048, 256, 0, stream>>>(pk, WB, BS);
  prep_wqT<<<64, 256, 0, stream>>>((const float*)d_in[1], (const float*)d_in[3],
                                   (const float*)d_in[6], WqT);
  cvt_x_t<<<4096, 256, 0, stream>>>(x, xb, xT, spart);
  ksvs<<<dim3(32, 2), 512, 0, stream>>>(WB, spart, ksv);
  // Gram: G[tb] = xT[tb] * xT[tb]^T  (full, 64x128 tiles, K=1024)
  gemm_n<16, 8, true, false><<<1024, 256, 0, stream>>>(
      xT, 524288, xT, 524288, nullptr, nullptr, Gb, nullptr, 262144);
  // KG[tb] = K' * G[tb]
  gemm_n<8, 8, true, false><<<1024, 256, 0, stream>>>(
      WB + 262144, 0, Gb, 262144, nullptr, nullptr, KGb, nullptr, 262144);
  kvz<<<256, 256, 0, stream>>>(KGb, WB, BS, ksv, ZT, cpart);
  // VT[tb] = ZT[tb] * WqT^T
  gemm_n<8, 8, true, false><<<1024, 256, 0, stream>>>(
      ZT, 262144, WqT, 0, nullptr, nullptr, VT, nullptr, 262144);
  // out[tb] = xb[tb] * VT[tb]^T + (bp' + sum_h cpart)  (f32 out)
  gemm_n<8, 16, false, true><<<2048, 256, 0, stream>>>(
      xb, 524288, VT, 262144, BS, cpart, nullptr, (float*)d_out, 524288);
}

// Round 9
// 134.633 us; speedup vs baseline: 1.1617x; 1.0707x over previous
//
#include <hip/hip_runtime.h>

#define T_ 4
#define B_ 8
#define N_ 1024
#define C_ 512
#define H_ 8
#define D_ 64
#define M_ (T_*B_*N_)   // 32768 rows
#define TB_ (T_*B_)     // 32

typedef __bf16 bf16;
typedef __bf16 bf16x4 __attribute__((ext_vector_type(4)));
typedef __bf16 bf16x8 __attribute__((ext_vector_type(8)));
typedef float f32x4 __attribute__((ext_vector_type(4)));

__device__ __forceinline__ void gload16(const void* g, void* l) {
  __builtin_amdgcn_global_load_lds(
      (const __attribute__((address_space(1))) void*)g,
      (__attribute__((address_space(3))) void*)l, 16, 0, 0);
}

struct PtrPack { const float* p[24]; };

// ---- merged prep: blocks [0,2048) fold BN into all 4 weight mats;
//      blocks [2048,2112) build WqT[c][d] = Wq[d][c]*sq[d] ----
__global__ __launch_bounds__(256)
void prep_m(PtrPack pk, bf16* __restrict__ WB, float* __restrict__ BS,
            bf16* __restrict__ WqT) {
  const int t = threadIdx.x;
  if (blockIdx.x < 2048) {
    const int mat = blockIdx.x >> 9, d = blockIdx.x & 511;
    const float* W    = pk.p[6*mat + 0];
    const float* b    = pk.p[6*mat + 1];
    const float* g    = pk.p[6*mat + 2];
    const float* beta = pk.p[6*mat + 3];
    const float* mu   = pk.p[6*mat + 4];
    const float* var  = pk.p[6*mat + 5];
    float s = g[d] * rsqrtf(var[d] + 1e-5f);
    if (t == 0) BS[mat*512 + d] = (b[d] - mu[d]) * s + beta[d];
    bf16* Wout = WB + (size_t)mat * 262144 + (size_t)d * 512;
    for (int c = t; c < 512; c += 256)
      Wout[c] = (bf16)(W[(size_t)d * 512 + c] * s);
    return;
  }
  // WqT part
  const int e = blockIdx.x - 2048;
  const int di = e >> 3, ci = e & 7;
  __shared__ float lds[64][65];
  const float* W = pk.p[0];
  const float* g = pk.p[2];
  const float* var = pk.p[5];
  const int rgrp = t >> 4, k = t & 15;
#pragma unroll
  for (int p = 0; p < 4; p++) {
    int r = p * 16 + rgrp;
    int d = di * 64 + r;
    float s = g[d] * rsqrtf(var[d] + 1e-5f);
    float4 v = *(const float4*)(W + (size_t)d * 512 + ci * 64 + k * 4);
    lds[r][k*4+0] = v.x * s; lds[r][k*4+1] = v.y * s;
    lds[r][k*4+2] = v.z * s; lds[r][k*4+3] = v.w * s;
  }
  __syncthreads();
#pragma unroll
  for (int p = 0; p < 16; p++) {
    int c = p * 4 + (t >> 6), dd = t & 63;
    WqT[(size_t)(ci*64 + c) * 512 + di*64 + dd] = (bf16)lds[dd][c];
  }
}

// ---- x -> xb + xT + col-sum partials ----
__global__ __launch_bounds__(256)
void cvt_x_t(const float* __restrict__ x, bf16* __restrict__ xb,
             bf16* __restrict__ xT, float* __restrict__ spart) {
  const int bid = blockIdx.x;
  const int tb = bid >> 7, nc = (bid >> 3) & 15, cc = bid & 7;
  const int t = threadIdx.x;
  __shared__ float lds[64][65];
  __shared__ float sred[16][64];
  const float* xbase = x + (size_t)tb * 524288 + (size_t)nc * 64 * 512 + cc * 64;
  bf16* xbb = xb + (size_t)tb * 524288 + (size_t)nc * 64 * 512 + cc * 64;
  bf16* xTb = xT + (size_t)tb * 524288 + (size_t)(cc * 64) * 1024 + nc * 64;
  const int rgrp = t >> 4, k = t & 15;
  float s0 = 0, s1 = 0, s2 = 0, s3 = 0;
#pragma unroll
  for (int p = 0; p < 4; p++) {
    int r = p * 16 + rgrp;
    float4 v = *(const float4*)(xbase + (size_t)r * 512 + k * 4);
    bf16x4 o; o[0]=(bf16)v.x; o[1]=(bf16)v.y; o[2]=(bf16)v.z; o[3]=(bf16)v.w;
    *(bf16x4*)(xbb + (size_t)r * 512 + k * 4) = o;
    lds[r][k*4+0]=v.x; lds[r][k*4+1]=v.y; lds[r][k*4+2]=v.z; lds[r][k*4+3]=v.w;
    s0 += v.x; s1 += v.y; s2 += v.z; s3 += v.w;
  }
  sred[rgrp][k*4+0]=s0; sred[rgrp][k*4+1]=s1; sred[rgrp][k*4+2]=s2; sred[rgrp][k*4+3]=s3;
  __syncthreads();
#pragma unroll
  for (int p = 0; p < 16; p++) {
    int c = p * 4 + (t >> 6), n = t & 63;
    xTb[(size_t)c * 1024 + n] = (bf16)lds[n][c];
  }
  if (t < 64) {
    float tot = 0;
#pragma unroll
    for (int rg = 0; rg < 16; rg++) tot += sred[rg][t];
    spart[(size_t)((tb*8 + cc)*16 + nc) * 64 + t] = tot;
  }
}

// =====================================================================
// gram_ksvs: blocks [0,640): SYM Gram G[tb] = xT xT^T with 64x128 tiles,
//   only mi>=2ni (20/32), mirror-store transposed tile via LDS bounce.
// blocks [640,704): ksvs: ksv[m][tb][d] = sum_c W'[m][d,c]*s[tb][c].
// =====================================================================
__global__ __launch_bounds__(256)
void gram_ksvs(const bf16* __restrict__ xT, const bf16* __restrict__ WB,
               const float* __restrict__ spart, bf16* __restrict__ Gb,
               float* __restrict__ ksv) {
  const int t = threadIdx.x;
  __shared__ __align__(16) char smem[24576];
  if (blockIdx.x >= 640) {
    // ---- ksvs (256 threads, 2 channels each) ----
    const int e = blockIdx.x - 640, tb = e >> 1, m = e & 1;
    float* sl = (float*)smem;     // [512]
#pragma unroll
    for (int half = 0; half < 2; half++) {
      int c = t + half * 256, cc = c >> 6, cl = c & 63;
      float tot = 0;
#pragma unroll
      for (int ncf = 0; ncf < 16; ncf++)
        tot += spart[(size_t)((tb*8 + cc)*16 + ncf) * 64 + cl];
      sl[c] = tot;
    }
    __syncthreads();
#pragma unroll
    for (int half = 0; half < 2; half++) {
      int d = t + half * 256;
      const bf16* Wrow = WB + (size_t)(m + 1) * 262144 + (size_t)d * 512;
      float acc = 0;
      for (int k = 0; k < 512; k += 8) {
        bf16x8 wv = *(const bf16x8*)(Wrow + k);
#pragma unroll
        for (int i = 0; i < 8; i++) acc += (float)wv[i] * sl[k + i];
      }
      ksv[m * 16384 + tb * 512 + d] = acc;
    }
    return;
  }
  // ---- SYM Gram tile ----
  constexpr int K = 1024;
  const int bid = blockIdx.x;
  const int xcd = bid & 7, j9 = bid >> 3;
  const int bat = xcd + 8 * (j9 / 20);
  const int tile = j9 % 20;
  int mi, ni;
  if (tile < 8)       { mi = tile;          ni = 0; }
  else if (tile < 14) { mi = tile - 8 + 2;  ni = 1; }
  else if (tile < 18) { mi = tile - 14 + 4; ni = 2; }
  else                { mi = tile - 18 + 6; ni = 3; }
  const bf16* A = xT + (size_t)bat * 524288;
  const int m0 = mi * 64, n0 = ni * 128;
  bf16* As = (bf16*)smem;              // [64][64]   8 KB
  bf16* Bs = (bf16*)(smem + 8192);     // [128][64] 16 KB
  const int w = t >> 6, l = t & 63;
  const int wm = w >> 1, wn = w & 1;
  const int lr = l & 15, lq = l >> 4, l7 = l & 7, lh = l >> 3;
  const int srcc = (l7 ^ lh) * 8;
  f32x4 acc[2][4] = {};
  for (int kt = 0; kt < 16; kt++) {
#pragma unroll
    for (int i = 0; i < 2; i++) {
      int rb = w * 16 + i * 8;
      gload16(A + (size_t)(m0 + rb + lh) * K + kt * 64 + srcc, &As[rb * 64]);
    }
#pragma unroll
    for (int i = 0; i < 4; i++) {
      int rb = w * 32 + i * 8;
      gload16(A + (size_t)(n0 + rb + lh) * K + kt * 64 + srcc, &Bs[rb * 64]);
    }
    __syncthreads();
    bf16x8 af[2][2], bv[4][2];
#pragma unroll
    for (int f = 0; f < 2; f++) {
      int ra = wm * 32 + f * 16 + lr;
#pragma unroll
      for (int s = 0; s < 2; s++)
        af[f][s] = *(const bf16x8*)&As[ra * 64 + (((s*4+lq) ^ (ra & 7)) * 8)];
    }
#pragma unroll
    for (int f = 0; f < 4; f++) {
      int rb2 = wn * 64 + f * 16 + lr;
#pragma unroll
      for (int s = 0; s < 2; s++)
        bv[f][s] = *(const bf16x8*)&Bs[rb2 * 64 + (((s*4+lq) ^ (rb2 & 7)) * 8)];
    }
#pragma unroll
    for (int mt = 0; mt < 2; mt++)
#pragma unroll
      for (int nt = 0; nt < 4; nt++)
#pragma unroll
        for (int s = 0; s < 2; s++)
          acc[mt][nt] = __builtin_amdgcn_mfma_f32_16x16x32_bf16(
              af[mt][s], bv[nt][s], acc[mt][nt], 0, 0, 0);
    __syncthreads();
  }
  // direct store (64x128 at m0,n0)
  bf16* ob = Gb + (size_t)bat * 262144;
#pragma unroll
  for (int mt = 0; mt < 2; mt++)
#pragma unroll
    for (int nt = 0; nt < 4; nt++) {
      int j = n0 + wn * 64 + nt * 16 + lr;
      size_t mrow = (size_t)m0 + wm * 32 + mt * 16 + lq * 4;
#pragma unroll
      for (int r = 0; r < 4; r++)
        ob[(mrow + r) * 512 + j] = (bf16)acc[mt][nt][r];
    }
  // mirror store (128x64 at n0,m0) via swizzled LDS bounce
  bf16* TB = (bf16*)smem;   // [128][64] = 16 KB
#pragma unroll
  for (int mt = 0; mt < 2; mt++)
#pragma unroll
    for (int nt = 0; nt < 4; nt++) {
      int a = wn * 64 + nt * 16 + lr;            // col of C = row of mirror
#pragma unroll
      for (int r = 0; r < 4; r++) {
        int b = wm * 32 + mt * 16 + lq * 4 + r;  // row of C = col of mirror
        TB[(a * 64 + b) ^ ((a & 7) << 3)] = (bf16)acc[mt][nt][r];
      }
    }
  __syncthreads();
  const int rowa = t >> 1, half = t & 1;
#pragma unroll
  for (int i = 0; i < 4; i++) {
    int c8 = half * 4 + i;
    bf16x8 v = *(const bf16x8*)&TB[(rowa * 64 + c8 * 8) ^ ((rowa & 7) << 3)];
    *(bf16x8*)(ob + (size_t)(n0 + rowa) * 512 + m0 + c8 * 8) = v;
  }
}

// =====================================================================
// Batched 64x128-tile GEMM, BK=64, 24 KB LDS single-buffered,
// chunk-XOR swizzle, gload_lds staging, XCD-clustered batches.
// __launch_bounds__(256,6): target 6 blocks/CU (VGPR cap 85).
// =====================================================================
template <int NKT, int MTILES, bool BF16OUT, bool BIAS>
__global__ __launch_bounds__(256, 6)
void gemm_n(const bf16* __restrict__ Abase, size_t Astr,
            const bf16* __restrict__ Btbase, size_t Btstr,
            const float* __restrict__ BSb, const float* __restrict__ cpart,
            bf16* __restrict__ ob, float* __restrict__ of, size_t Ostr) {
  constexpr int K = NKT * 64;
  constexpr int PERB = MTILES * 4;
  const int bid = blockIdx.x;
  const int xcd = bid & 7, j9 = bid >> 3;
  const int bat = xcd + 8 * (j9 / PERB);
  const int tile = j9 % PERB;
  const int mi = tile >> 2, ni = tile & 3;
  const bf16* A = Abase + (size_t)bat * Astr;
  const bf16* Bt = Btbase + (size_t)bat * Btstr;
  const int m0 = mi * 64, n0 = ni * 128;
  __shared__ __align__(16) bf16 As[64][64];    //  8 KB
  __shared__ __align__(16) bf16 Bs[128][64];   // 16 KB
  const int tid = threadIdx.x, w = tid >> 6, l = tid & 63;
  const int wm = w >> 1, wn = w & 1;
  const int lr = l & 15, lq = l >> 4, l7 = l & 7, lh = l >> 3;
  const int srcc = (l7 ^ lh) * 8;
  f32x4 acc[2][4] = {};
  for (int kt = 0; kt < NKT; kt++) {
#pragma unroll
    for (int i = 0; i < 2; i++) {
      int rb = w * 16 + i * 8;
      gload16(A + (size_t)(m0 + rb + lh) * K + kt * 64 + srcc, &As[rb][0]);
    }
#pragma unroll
    for (int i = 0; i < 4; i++) {
      int rb = w * 32 + i * 8;
      gload16(Bt + (size_t)(n0 + rb + lh) * K + kt * 64 + srcc, &Bs[rb][0]);
    }
    __syncthreads();
    bf16x8 af[2][2], bv[4][2];
#pragma unroll
    for (int f = 0; f < 2; f++) {
      int ra = wm * 32 + f * 16 + lr;
#pragma unroll
      for (int s = 0; s < 2; s++)
        af[f][s] = *(const bf16x8*)&As[ra][((s*4+lq) ^ (ra & 7)) * 8];
    }
#pragma unroll
    for (int f = 0; f < 4; f++) {
      int rb2 = wn * 64 + f * 16 + lr;
#pragma unroll
      for (int s = 0; s < 2; s++)
        bv[f][s] = *(const bf16x8*)&Bs[rb2][((s*4+lq) ^ (rb2 & 7)) * 8];
    }
#pragma unroll
    for (int mt = 0; mt < 2; mt++)
#pragma unroll
      for (int nt = 0; nt < 4; nt++)
#pragma unroll
        for (int s = 0; s < 2; s++)
          acc[mt][nt] = __builtin_amdgcn_mfma_f32_16x16x32_bf16(
              af[mt][s], bv[nt][s], acc[mt][nt], 0, 0, 0);
    __syncthreads();
  }

  float bja[4];
  if constexpr (BIAS) {
#pragma unroll
    for (int nt = 0; nt < 4; nt++) {
      int j = n0 + wn * 64 + nt * 16 + lr;
      float bj = BSb[1536 + j];
#pragma unroll
      for (int h = 0; h < 8; h++)
        bj += cpart[(size_t)(bat * 8 + h) * 512 + j];
      bja[nt] = bj;
    }
  }
#pragma unroll
  for (int mt = 0; mt < 2; mt++)
#pragma unroll
    for (int nt = 0; nt < 4; nt++) {
      int j = n0 + wn * 64 + nt * 16 + lr;
      size_t mrow = (size_t)m0 + wm * 32 + mt * 16 + lq * 4;
#pragma unroll
      for (int r = 0; r < 4; r++) {
        if constexpr (BF16OUT)
          ob[(size_t)bat * Ostr + (mrow + r) * 512 + j] = (bf16)acc[mt][nt][r];
        else
          of[(size_t)bat * Ostr + (mrow + r) * 512 + j] =
              acc[mt][nt][r] + (BIAS ? bja[nt] : 0.f);
      }
    }
}

// =====================================================================
// kvz: per (tb,h): kv = (KG_h V_h^T + rank-1)/N + bk bv^T; Z_h = kv P_h^T
// =====================================================================
__global__ __launch_bounds__(256)
void kvz(const bf16* __restrict__ KGb, const bf16* __restrict__ WB,
         const float* __restrict__ BS, const float* __restrict__ ksv,
         bf16* __restrict__ ZT, float* __restrict__ cpart) {
  const int gid = blockIdx.x, tb = gid >> 3, h = gid & 7;
  const int t = threadIdx.x, w = t >> 6, l = t & 63;
  const int lr = l & 15, lq = l >> 4;
  __shared__ __align__(16) char lds[65536 + 65536 + 8192];
  bf16* bufA = (bf16*)lds;
  bf16* bufV = (bf16*)(lds + 65536);
  bf16* kvb  = (bf16*)(lds + 131072);

#pragma unroll
  for (int i = 0; i < 16; i++) {
    int r = i * 4 + w;
    gload16(KGb + (size_t)tb * 262144 + (size_t)(64*h + r) * 512 + ((l ^ (r & 7)) * 8),
            bufA + r * 512);
    gload16(WB + 2u * 262144 + (size_t)(64*h + r) * 512 + ((l ^ (r & 7)) * 8),
            bufV + r * 512);
  }
  __syncthreads();

  f32x4 acc2[4][4] = {};
#pragma unroll
  for (int ks = 0; ks < 4; ks++) {
    int gch = w * 16 + ks * 4 + lq;
    bf16x8 af2[4], bv2[4];
#pragma unroll
    for (int mf = 0; mf < 4; mf++) {
      int d = mf * 16 + lr;
      af2[mf] = *(const bf16x8*)&bufA[d * 512 + ((gch ^ (d & 7)) * 8)];
    }
#pragma unroll
    for (int nf = 0; nf < 4; nf++) {
      int e = nf * 16 + lr;
      bv2[nf] = *(const bf16x8*)&bufV[e * 512 + ((gch ^ (e & 7)) * 8)];
    }
#pragma unroll
    for (int mf = 0; mf < 4; mf++)
#pragma unroll
      for (int nf = 0; nf < 4; nf++)
        acc2[mf][nf] = __builtin_amdgcn_mfma_f32_16x16x32_bf16(
            af2[mf], bv2[nf], acc2[mf][nf], 0, 0, 0);
  }
  __syncthreads();

  float* part = (float*)lds + w * 4096;
#pragma unroll
  for (int mf = 0; mf < 4; mf++)
#pragma unroll
    for (int nf = 0; nf < 4; nf++)
#pragma unroll
      for (int r = 0; r < 4; r++) {
        int d = mf * 16 + lq * 4 + r, e = nf * 16 + lr;
        part[d * 64 + e] = acc2[mf][nf][r];
      }
  __syncthreads();
  {
    const float inv = 1.f / 1024.f;
    const float* pb = (const float*)lds;
#pragma unroll
    for (int jj = 0; jj < 16; jj++) {
      int flat = jj * 256 + t, d = flat >> 6, e = flat & 63;
      float s = pb[flat] + pb[4096 + flat] + pb[8192 + flat] + pb[12288 + flat];
      float ksh = ksv[tb * 512 + 64*h + d];
      float vsh = ksv[16384 + tb * 512 + 64*h + e];
      float bkh = BS[512 + 64*h + d];
      float bvh = BS[1024 + 64*h + e];
      float kv = (s + ksh * bvh + bkh * vsh) * inv + bkh * bvh;
      kvb[d * 64 + (((e >> 3) ^ (d & 7)) * 8 + (e & 7))] = (bf16)kv;
    }
  }
  __syncthreads();

#pragma unroll
  for (int i = 0; i < 16; i++) {
    int rb = i * 32 + w * 8;
    int r = rb + (l >> 3);
    gload16(WB + 3u * 262144 + (size_t)r * 512 + 64*h + (((l & 7) ^ (r & 7)) * 8),
            bufA + rb * 64);
  }
  __syncthreads();

  f32x4 acc3[4][8] = {};
#pragma unroll
  for (int s = 0; s < 2; s++) {
    bf16x8 af3[4];
#pragma unroll
    for (int mf = 0; mf < 4; mf++) {
      int d = mf * 16 + lr;
      af3[mf] = *(const bf16x8*)&kvb[d * 64 + (((s*4+lq) ^ (d & 7)) * 8)];
    }
#pragma unroll
    for (int nf = 0; nf < 8; nf++) {
      int jj = w * 128 + nf * 16 + lr;
      bf16x8 b3 = *(const bf16x8*)&bufA[jj * 64 + (((s*4+lq) ^ (jj & 7)) * 8)];
#pragma unroll
      for (int mf = 0; mf < 4; mf++)
        acc3[mf][nf] = __builtin_amdgcn_mfma_f32_16x16x32_bf16(
            af3[mf], b3, acc3[mf][nf], 0, 0, 0);
    }
  }

  bf16* zbase = ZT + (size_t)tb * 262144 + 64*h;
#pragma unroll
  for (int nf = 0; nf < 8; nf++) {
    int jj = w * 128 + nf * 16 + lr;
    float cp = 0.f;
#pragma unroll
    for (int mf = 0; mf < 4; mf++) {
      bf16x4 o;
#pragma unroll
      for (int r = 0; r < 4; r++) {
        o[r] = (bf16)acc3[mf][nf][r];
        cp += acc3[mf][nf][r] * BS[64*h + mf*16 + lq*4 + r];
      }
      *(bf16x4*)(zbase + (size_t)jj * 512 + mf * 16 + lq * 4) = o;
    }
    cp += __shfl_xor(cp, 16);
    cp += __shfl_xor(cp, 32);
    if (lq == 0) cpart[(size_t)(tb * 8 + h) * 512 + jj] = cp;
  }
}

extern "C" void kernel_launch(void* const* d_in, const int* in_sizes, int n_in,
                              void* d_out, int out_size, void* d_ws, size_t ws_size,
                              hipStream_t stream) {
  const float* x = (const float*)d_in[0];
  char* ws = (char*)d_ws;
  bf16*  xb    = (bf16*)(ws + 0);             // [32][1024][512]
  bf16*  xT    = (bf16*)(ws + 33554432);      // [32][512][1024]
  bf16*  Gb    = (bf16*)(ws + 67108864);      // [32][512][512]
  bf16*  KGb   = (bf16*)(ws + 83886080);      // [32][512][512]
  bf16*  ZT    = (bf16*)(ws + 100663296);     // [32][512][512]
  bf16*  VT    = (bf16*)(ws + 117440512);     // [32][512][512]
  bf16*  WB    = (bf16*)(ws + 134217728);     // [4][512][512]
  bf16*  WqT   = (bf16*)(ws + 136314880);     // [512][512]
  float* BS    = (float*)(ws + 136839168);    // [4][512]
  float* ksv   = (float*)(ws + 136847360);    // [2][32][512]
  float* cpart = (float*)(ws + 136978432);    // [32][8][512]
  float* spart = (float*)(ws + 137502720);    // [32*8*16][64]
  (void)in_sizes; (void)n_in; (void)out_size; (void)ws_size;

  PtrPack pk;
  for (int i = 0; i < 24; i++) pk.p[i] = (const float*)d_in[1 + i];

  prep_m<<<2112, 256, 0, stream>>>(pk, WB, BS, WqT);
  cvt_x_t<<<4096, 256, 0, stream>>>(x, xb, xT, spart);
  // SYM Gram (640 blocks) + ksvs (64 blocks)
  gram_ksvs<<<704, 256, 0, stream>>>(xT, WB, spart, Gb, ksv);
  // KG[tb] = K' * G[tb]
  gemm_n<8, 8, true, false><<<1024, 256, 0, stream>>>(
      WB + 262144, 0, Gb, 262144, nullptr, nullptr, KGb, nullptr, 262144);
  kvz<<<256, 256, 0, stream>>>(KGb, WB, BS, ksv, ZT, cpart);
  // VT[tb] = ZT[tb] * WqT^T
  gemm_n<8, 8, true, false><<<1024, 256, 0, stream>>>(
      ZT, 262144, WqT, 0, nullptr, nullptr, VT, nullptr, 262144);
  // out[tb] = xb[tb] * VT[tb]^T + (bp' + sum_h cpart)  (f32 out)
  gemm_n<8, 16, false, true><<<2048, 256, 0, stream>>>(
      xb, 524288, VT, 262144, BS, cpart, nullptr, (float*)d_out, 524288);
}